// Round 9
// baseline (53.829 us; speedup 1.0000x reference)
//
#include <hip/hip_runtime.h>
#include <math.h>

#define BINS 10
#define BLOCK 256
// each block consumes BLOCK*4 float4s = 4096 elements
#define TILE_F4 (BLOCK * 4)

// ---------------------------------------------------------------------------
// Pass 1. R8 math (fast transcendentals, single packed ds_add_u64 per elem:
// (count:1<<40)|fixedpoint_bce(2^-20)) with BATCHED loads: all 8 dwordx4
// loads issued before any compute -> 8KB outstanding per wave -> BW-limited
// regime instead of latency-limited (R6/R8's common ~50us floor).
// ---------------------------------------------------------------------------

__global__ __launch_bounds__(BLOCK) void ghm_pass1(
        const float4* __restrict__ x4, const float4* __restrict__ t4,
        const float* __restrict__ xs, const float* __restrict__ ts,
        float* __restrict__ psum, unsigned int* __restrict__ pcnt,
        int nvec, int total) {
    __shared__ unsigned long long hist[BINS * BLOCK];   // 20 KiB
    const int tid = threadIdx.x;
#pragma unroll
    for (int b = 0; b < BINS; ++b) hist[b * BLOCK + tid] = 0ull;
    __syncthreads();

    const float L2E    = 1.44269504088896f;   // log2(e)
    const float LN2    = 0.69314718055995f;   // ln(2)
    const float QSCALE = 1048576.0f;          // 2^20 fixed-point scale

    auto proc = [&](float xv, float tv) {
        float e   = __builtin_amdgcn_exp2f(-L2E * __builtin_fabsf(xv)); // e^-|x|
        float ope = 1.0f + e;
        float r   = __builtin_amdgcn_rcpf(ope);           // 1/(1+e)
        float sig = (xv >= 0.0f) ? r : e * r;             // stable sigmoid
        float g   = __builtin_fabsf(sig - tv);            // in [0,1]
        int bi = (int)(g * 9.9999f);
        bi = bi > (BINS - 1) ? (BINS - 1) : bi;           // ulp safety clamp
        float l2  = __builtin_amdgcn_logf(ope);           // log2(1+e)
        float bce = __builtin_fmaf(-xv, tv, __builtin_fmaxf(xv, 0.0f));
        bce = __builtin_fmaf(LN2, l2, bce);               // + ln(1+e)
        unsigned int q = (unsigned int)__builtin_fmaf(bce, QSCALE, 0.5f);
        atomicAdd(&hist[bi * BLOCK + tid],
                  (1ull << 40) | (unsigned long long)q);  // native ds_add_u64
    };

    const int ntiles = nvec / TILE_F4;        // full tiles only

    for (int tile = blockIdx.x; tile < ntiles; tile += gridDim.x) {
        const int p = tile * TILE_F4 + tid;
        // ---- batch ALL loads before ANY compute (MLP: 8KB/wave in flight)
        float4 X0 = x4[p];
        float4 X1 = x4[p + BLOCK];
        float4 X2 = x4[p + 2 * BLOCK];
        float4 X3 = x4[p + 3 * BLOCK];
        float4 T0 = t4[p];
        float4 T1 = t4[p + BLOCK];
        float4 T2 = t4[p + 2 * BLOCK];
        float4 T3 = t4[p + 3 * BLOCK];
        // ---- then 16 elements of compute + 16 fire-and-forget DS atomics
        proc(X0.x, T0.x); proc(X0.y, T0.y); proc(X0.z, T0.z); proc(X0.w, T0.w);
        proc(X1.x, T1.x); proc(X1.y, T1.y); proc(X1.z, T1.z); proc(X1.w, T1.w);
        proc(X2.x, T2.x); proc(X2.y, T2.y); proc(X2.z, T2.z); proc(X2.w, T2.w);
        proc(X3.x, T3.x); proc(X3.y, T3.y); proc(X3.z, T3.z); proc(X3.w, T3.w);
    }
    // tail: elements not covered by full tiles (empty for the bench shape)
    for (int j = ntiles * TILE_F4 * 4 + blockIdx.x * BLOCK + tid;
         j < total; j += gridDim.x * BLOCK)
        proc(xs[j], ts[j]);

    __syncthreads();

    // Block reduce. Packed fields can't overflow: <=4096 elems/block ->
    // count < 2^13 at bit 40, sum < 4096*7*2^20 < 2^35 < 2^40.
    unsigned long long v[BINS];
#pragma unroll
    for (int b = 0; b < BINS; ++b) v[b] = hist[b * BLOCK + tid];
    __syncthreads();                                    // reads done -> reuse

    const int lane = tid & 63;
    const int wid  = tid >> 6;
#pragma unroll
    for (int b = 0; b < BINS; ++b) {
        unsigned long long s = v[b];
#pragma unroll
        for (int off = 32; off > 0; off >>= 1)
            s += __shfl_down(s, off);
        if (lane == 0) hist[wid * BINS + b] = s;
    }
    __syncthreads();
    if (tid < BINS) {
        unsigned long long tot = 0ull;
#pragma unroll
        for (int w = 0; w < BLOCK / 64; ++w) tot += hist[w * BINS + tid];
        unsigned long long sum_fp = tot & ((1ull << 40) - 1ull);
        unsigned int       cntv   = (unsigned int)(tot >> 40);
        psum[(size_t)blockIdx.x * BINS + tid] =
            (float)((double)sum_fp * 9.5367431640625e-7);   // * 2^-20
        pcnt[(size_t)blockIdx.x * BINS + tid] = cntv;
    }
}

// ---------------------------------------------------------------------------
// Pass 2: single strided sweep over partials, wave+LDS reduce, beta math
// exactly as the reference (fp32), final scalar.
// ---------------------------------------------------------------------------

__global__ __launch_bounds__(BLOCK) void ghm_pass2(
        const float* __restrict__ psum, const unsigned int* __restrict__ pcnt,
        float* __restrict__ out, int nblocks, float Nf, double inv_total) {
    double       s[BINS];
    unsigned int c[BINS];
#pragma unroll
    for (int b = 0; b < BINS; ++b) { s[b] = 0.0; c[b] = 0u; }

    for (int i = threadIdx.x; i < nblocks; i += BLOCK) {
#pragma unroll
        for (int b = 0; b < BINS; ++b) {
            s[b] += (double)psum[(size_t)i * BINS + b];
            c[b] += pcnt[(size_t)i * BINS + b];
        }
    }

    __shared__ double       ls[BLOCK / 64][BINS];
    __shared__ unsigned int lc[BLOCK / 64][BINS];
    const int lane = threadIdx.x & 63;
    const int wid  = threadIdx.x >> 6;
#pragma unroll
    for (int b = 0; b < BINS; ++b) {
        double       sb = s[b];
        unsigned int cb = c[b];
#pragma unroll
        for (int off = 32; off > 0; off >>= 1) {
            sb += __shfl_down(sb, off);
            cb += __shfl_down(cb, off);
        }
        if (lane == 0) { ls[wid][b] = sb; lc[wid][b] = cb; }
    }
    __syncthreads();

    if (threadIdx.x == 0) {
        double             bin_sum[BINS];
        unsigned long long bin_cnt[BINS];
#pragma unroll
        for (int b = 0; b < BINS; ++b) {
            double ts = 0.0;
            unsigned long long tc = 0;
#pragma unroll
            for (int w = 0; w < BLOCK / 64; ++w) { ts += ls[w][b]; tc += lc[w][b]; }
            bin_sum[b] = ts;
            bin_cnt[b] = tc;
        }
        float nonempty = 0.0f;
#pragma unroll
        for (int b = 0; b < BINS; ++b) nonempty += (bin_cnt[b] > 0) ? 1.0f : 0.0f;
        double acc = 0.0;
#pragma unroll
        for (int b = 0; b < BINS; ++b) {
            float bc   = (float)bin_cnt[b];            // reference keeps fp32
            float gd   = fmaxf(bc * nonempty, 1e-6f);
            float beta = Nf / gd;
            acc += (double)beta * bin_sum[b];
        }
        out[0] = (float)(acc * inv_total);
    }
}

// ---------------------------------------------------------------------------

extern "C" void kernel_launch(void* const* d_in, const int* in_sizes, int n_in,
                              void* d_out, int out_size, void* d_ws, size_t ws_size,
                              hipStream_t stream) {
    const float* x = (const float*)d_in[0];
    const float* t = (const float*)d_in[1];
    const int total = in_sizes[0];          // 1048576 * 16
    const int nvec  = total / 4;
    const int N     = total / 16;           // x.shape[0] (first dim)

    // one block per full tile (4096 for the bench shape), capped by ws
    int nblocks = (nvec + TILE_F4 - 1) / TILE_F4;
    if (nblocks < 1) nblocks = 1;
    size_t per_block = (size_t)BINS * (sizeof(float) + sizeof(unsigned int));
    if ((size_t)nblocks * per_block > ws_size) {
        nblocks = (int)(ws_size / per_block);
        if (nblocks < 1) nblocks = 1;
    }

    float*        psum = (float*)d_ws;
    unsigned int* pcnt = (unsigned int*)((char*)d_ws +
                          (size_t)nblocks * BINS * sizeof(float));

    ghm_pass1<<<nblocks, BLOCK, 0, stream>>>(
        (const float4*)x, (const float4*)t, x, t, psum, pcnt, nvec, total);
    ghm_pass2<<<1, BLOCK, 0, stream>>>(
        psum, pcnt, (float*)d_out, nblocks, (float)N, 1.0 / (double)total);
}

// Round 11
// 43.416 us; speedup vs baseline: 1.2398x; 1.2398x over previous
//
#include <hip/hip_runtime.h>
#include <math.h>

#define BINS 10
#define BLOCK 256
#define NBLK 2048

// ---------------------------------------------------------------------------
// Pass 1. Lean math (3 hw transcendentals) + single packed ds_add_u64/elem
// (count at bit 40 | fixed-point bce at 2^-20). NEW vs R9:
//  * register software-pipeline: iteration k+1's float4 pair is loaded
//    BEFORE iteration k's compute (sched_barrier pins it) -> HBM latency
//    overlaps compute instead of being serially exposed (R9 lesson:
//    VGPR=20 proved the compiler sank "batched" loads to use sites).
//  * 2048 blocks x 32 elems/thread -> epilogue amortized 8x, 8 blocks/CU.
// ---------------------------------------------------------------------------

__global__ __launch_bounds__(BLOCK) void ghm_pass1(
        const float4* __restrict__ x4, const float4* __restrict__ t4,
        const float* __restrict__ xs, const float* __restrict__ ts,
        float* __restrict__ psum, unsigned int* __restrict__ pcnt,
        int nvec, int total) {
    __shared__ unsigned long long hist[BINS * BLOCK];   // 20 KiB
    const int tid = threadIdx.x;
#pragma unroll
    for (int b = 0; b < BINS; ++b) hist[b * BLOCK + tid] = 0ull;
    __syncthreads();

    const float L2E    = 1.44269504088896f;   // log2(e)
    const float LN2    = 0.69314718055995f;   // ln(2)
    const float QSCALE = 1048576.0f;          // 2^20 fixed point
    unsigned long long* __restrict__ mycol = &hist[tid];

    auto proc = [&](float xv, float tv) {
        float e   = __builtin_amdgcn_exp2f(-L2E * __builtin_fabsf(xv)); // e^-|x|
        float ope = 1.0f + e;
        float r   = __builtin_amdgcn_rcpf(ope);           // 1/(1+e)
        float sig = (xv >= 0.0f) ? r : e * r;             // stable sigmoid
        float g   = __builtin_fabsf(sig - tv);            // [0,1]
        int bi = (int)(g * 9.9999f);
        bi = bi > (BINS - 1) ? (BINS - 1) : bi;           // ulp safety clamp
        float l2  = __builtin_amdgcn_logf(ope);           // log2(1+e)
        float bce = __builtin_fmaf(-xv, tv, __builtin_fmaxf(xv, 0.0f));
        bce = __builtin_fmaf(LN2, l2, bce);               // + ln(1+e)
        unsigned int q = (unsigned int)__builtin_fmaf(bce, QSCALE, 0.5f);
        atomicAdd(mycol + bi * BLOCK,
                  (1ull << 40) | (unsigned long long)q);  // native ds_add_u64
    };

    const int stride = gridDim.x * BLOCK;
    const int gid    = blockIdx.x * BLOCK + tid;

    if (gid < nvec) {
        float4 xc = x4[gid];
        float4 tc = t4[gid];
        for (int inext = gid + stride; inext < nvec; inext += stride) {
            // prefetch NEXT pair first; results are loop-carried so they
            // live in registers across the compute below
            float4 xn = x4[inext];
            float4 tn = t4[inext];
            __builtin_amdgcn_sched_barrier(0);   // pin: loads issue before compute
            proc(xc.x, tc.x); proc(xc.y, tc.y);
            proc(xc.z, tc.z); proc(xc.w, tc.w);
            xc = xn; tc = tn;
        }
        proc(xc.x, tc.x); proc(xc.y, tc.y);
        proc(xc.z, tc.z); proc(xc.w, tc.w);
    }
    // scalar tail (not hit for the bench shape)
    for (int j = nvec * 4 + gid; j < total; j += stride)
        proc(xs[j], ts[j]);

    __syncthreads();

    // Block reduce. Field safety: <=8192 elems/block -> count < 2^24 (bit
    // 40 field), sum <= 8192 * 7.4e6 ~ 6e10 < 2^40. No overflow.
    unsigned long long v[BINS];
#pragma unroll
    for (int b = 0; b < BINS; ++b) v[b] = hist[b * BLOCK + tid];
    __syncthreads();                                    // reads done -> reuse

    const int lane = tid & 63;
    const int wid  = tid >> 6;
#pragma unroll
    for (int b = 0; b < BINS; ++b) {
        unsigned long long s = v[b];
#pragma unroll
        for (int off = 32; off > 0; off >>= 1)
            s += __shfl_down(s, off);
        if (lane == 0) hist[wid * BINS + b] = s;
    }
    __syncthreads();
    if (tid < BINS) {
        unsigned long long tot = 0ull;
#pragma unroll
        for (int w = 0; w < BLOCK / 64; ++w) tot += hist[w * BINS + tid];
        unsigned long long sum_fp = tot & ((1ull << 40) - 1ull);
        unsigned int       cntv   = (unsigned int)(tot >> 40);
        psum[(size_t)blockIdx.x * BINS + tid] =
            (float)((double)sum_fp * 9.5367431640625e-7);   // * 2^-20
        pcnt[(size_t)blockIdx.x * BINS + tid] = cntv;
    }
}

// ---------------------------------------------------------------------------
// Pass 2: strided sweep over partials, wave+LDS reduce, fp32 beta math
// exactly as the reference, final scalar.
// ---------------------------------------------------------------------------

__global__ __launch_bounds__(BLOCK) void ghm_pass2(
        const float* __restrict__ psum, const unsigned int* __restrict__ pcnt,
        float* __restrict__ out, int nblocks, float Nf, double inv_total) {
    double       s[BINS];
    unsigned int c[BINS];
#pragma unroll
    for (int b = 0; b < BINS; ++b) { s[b] = 0.0; c[b] = 0u; }

    for (int i = threadIdx.x; i < nblocks; i += BLOCK) {
#pragma unroll
        for (int b = 0; b < BINS; ++b) {
            s[b] += (double)psum[(size_t)i * BINS + b];
            c[b] += pcnt[(size_t)i * BINS + b];
        }
    }

    __shared__ double       ls[BLOCK / 64][BINS];
    __shared__ unsigned int lc[BLOCK / 64][BINS];
    const int lane = threadIdx.x & 63;
    const int wid  = threadIdx.x >> 6;
#pragma unroll
    for (int b = 0; b < BINS; ++b) {
        double       sb = s[b];
        unsigned int cb = c[b];
#pragma unroll
        for (int off = 32; off > 0; off >>= 1) {
            sb += __shfl_down(sb, off);
            cb += __shfl_down(cb, off);
        }
        if (lane == 0) { ls[wid][b] = sb; lc[wid][b] = cb; }
    }
    __syncthreads();

    if (threadIdx.x == 0) {
        double             bin_sum[BINS];
        unsigned long long bin_cnt[BINS];
#pragma unroll
        for (int b = 0; b < BINS; ++b) {
            double ts = 0.0;
            unsigned long long tc = 0;
#pragma unroll
            for (int w = 0; w < BLOCK / 64; ++w) { ts += ls[w][b]; tc += lc[w][b]; }
            bin_sum[b] = ts;
            bin_cnt[b] = tc;
        }
        float nonempty = 0.0f;
#pragma unroll
        for (int b = 0; b < BINS; ++b) nonempty += (bin_cnt[b] > 0) ? 1.0f : 0.0f;
        double acc = 0.0;
#pragma unroll
        for (int b = 0; b < BINS; ++b) {
            float bc   = (float)bin_cnt[b];            // reference keeps fp32
            float gd   = fmaxf(bc * nonempty, 1e-6f);
            float beta = Nf / gd;
            acc += (double)beta * bin_sum[b];
        }
        out[0] = (float)(acc * inv_total);
    }
}

// ---------------------------------------------------------------------------

extern "C" void kernel_launch(void* const* d_in, const int* in_sizes, int n_in,
                              void* d_out, int out_size, void* d_ws, size_t ws_size,
                              hipStream_t stream) {
    const float* x = (const float*)d_in[0];
    const float* t = (const float*)d_in[1];
    const int total = in_sizes[0];          // 1048576 * 16
    const int nvec  = total / 4;
    const int N     = total / 16;           // x.shape[0] (first dim)

    int nblocks = NBLK;
    size_t per_block = (size_t)BINS * (sizeof(float) + sizeof(unsigned int));
    if ((size_t)nblocks * per_block > ws_size) {
        nblocks = (int)(ws_size / per_block);
        if (nblocks < 1) nblocks = 1;
    }

    float*        psum = (float*)d_ws;
    unsigned int* pcnt = (unsigned int*)((char*)d_ws +
                          (size_t)nblocks * BINS * sizeof(float));

    ghm_pass1<<<nblocks, BLOCK, 0, stream>>>(
        (const float4*)x, (const float4*)t, x, t, psum, pcnt, nvec, total);
    ghm_pass2<<<1, BLOCK, 0, stream>>>(
        psum, pcnt, (float*)d_out, nblocks, (float)N, 1.0 / (double)total);
}

// Round 12
// 39.545 us; speedup vs baseline: 1.3612x; 1.0979x over previous
//
#include <hip/hip_runtime.h>
#include <math.h>

#define BINS 10
#define BLOCK 256
#define NBLK 2048
#define DEPTH 4

// ---------------------------------------------------------------------------
// Pass 1. Lean math + single packed ds_add_u64/elem (count@bit40 | bce*2^20).
// NEW vs R11: 4-deep rotating load pipeline. Slot k: compute(pair k) then
// immediately reload pair k from 4 strides ahead, sched_barrier(0) pins the
// reload before slot k+1's compute. Steady state ~6 loads/thread in flight
// (vs 2 in R11) -> 3x the request rate; stall converts to overlap.
// (R6 vs R11 A/B proved the histogram mechanism irrelevant; the invariant
//  ~50us floor is load-latency convoying at 2 outstanding loads/wave.)
// ---------------------------------------------------------------------------

__global__ __launch_bounds__(BLOCK) void ghm_pass1(
        const float4* __restrict__ x4, const float4* __restrict__ t4,
        const float* __restrict__ xs, const float* __restrict__ ts,
        float* __restrict__ psum, unsigned int* __restrict__ pcnt,
        int nvec, int total) {
    __shared__ unsigned long long hist[BINS * BLOCK];   // 20 KiB
    const int tid = threadIdx.x;
#pragma unroll
    for (int b = 0; b < BINS; ++b) hist[b * BLOCK + tid] = 0ull;
    __syncthreads();

    const float L2E    = 1.44269504088896f;   // log2(e)
    const float LN2    = 0.69314718055995f;   // ln(2)
    const float QSCALE = 1048576.0f;          // 2^20 fixed point
    unsigned long long* __restrict__ mycol = &hist[tid];

    auto proc = [&](float xv, float tv) {
        float e   = __builtin_amdgcn_exp2f(-L2E * __builtin_fabsf(xv)); // e^-|x|
        float ope = 1.0f + e;
        float r   = __builtin_amdgcn_rcpf(ope);           // 1/(1+e)
        float sig = (xv >= 0.0f) ? r : e * r;             // stable sigmoid
        float g   = __builtin_fabsf(sig - tv);            // [0,1]
        int bi = (int)(g * 9.9999f);
        bi = bi > (BINS - 1) ? (BINS - 1) : bi;           // ulp safety clamp
        float l2  = __builtin_amdgcn_logf(ope);           // log2(1+e)
        float bce = __builtin_fmaf(-xv, tv, __builtin_fmaxf(xv, 0.0f));
        bce = __builtin_fmaf(LN2, l2, bce);               // + ln(1+e)
        unsigned int q = (unsigned int)__builtin_fmaf(bce, QSCALE, 0.5f);
        atomicAdd(mycol + bi * BLOCK,
                  (1ull << 40) | (unsigned long long)q);  // native ds_add_u64
    };

    const int stride = gridDim.x * BLOCK;                 // in float4 units
    const int gid    = blockIdx.x * BLOCK + tid;

    // Main pipelined body: requires at least DEPTH strides of work.
    // For the bench shape: nvec=4.19M, stride=524288, 8 strides/thread.
    int i = gid;
    if (gid + (DEPTH - 1) * stride < nvec) {
        // ---- prologue: fill 4 slots (8 loads back-to-back)
        float4 X0 = x4[i];              float4 T0 = t4[i];
        float4 X1 = x4[i + stride];     float4 T1 = t4[i + stride];
        float4 X2 = x4[i + 2 * stride]; float4 T2 = t4[i + 2 * stride];
        float4 X3 = x4[i + 3 * stride]; float4 T3 = t4[i + 3 * stride];
        __builtin_amdgcn_sched_barrier(0);
        // ---- steady state: compute slot, reload slot from DEPTH ahead
        int inext = i + DEPTH * stride;                   // next load index
        while (inext + 3 * stride < nvec) {
            proc(X0.x, T0.x); proc(X0.y, T0.y); proc(X0.z, T0.z); proc(X0.w, T0.w);
            X0 = x4[inext]; T0 = t4[inext]; inext += stride;
            __builtin_amdgcn_sched_barrier(0);
            proc(X1.x, T1.x); proc(X1.y, T1.y); proc(X1.z, T1.z); proc(X1.w, T1.w);
            X1 = x4[inext]; T1 = t4[inext]; inext += stride;
            __builtin_amdgcn_sched_barrier(0);
            proc(X2.x, T2.x); proc(X2.y, T2.y); proc(X2.z, T2.z); proc(X2.w, T2.w);
            X2 = x4[inext]; T2 = t4[inext]; inext += stride;
            __builtin_amdgcn_sched_barrier(0);
            proc(X3.x, T3.x); proc(X3.y, T3.y); proc(X3.z, T3.z); proc(X3.w, T3.w);
            X3 = x4[inext]; T3 = t4[inext]; inext += stride;
            __builtin_amdgcn_sched_barrier(0);
        }
        // ---- drain the 4 live slots
        proc(X0.x, T0.x); proc(X0.y, T0.y); proc(X0.z, T0.z); proc(X0.w, T0.w);
        proc(X1.x, T1.x); proc(X1.y, T1.y); proc(X1.z, T1.z); proc(X1.w, T1.w);
        proc(X2.x, T2.x); proc(X2.y, T2.y); proc(X2.z, T2.z); proc(X2.w, T2.w);
        proc(X3.x, T3.x); proc(X3.y, T3.y); proc(X3.z, T3.z); proc(X3.w, T3.w);
        // ---- leftover strided singles (when strides/thread % DEPTH != 0)
        for (i = inext; i < nvec; i += stride) {
            float4 xa = x4[i]; float4 ta = t4[i];
            proc(xa.x, ta.x); proc(xa.y, ta.y); proc(xa.z, ta.z); proc(xa.w, ta.w);
        }
    } else {
        for (; i < nvec; i += stride) {
            float4 xa = x4[i]; float4 ta = t4[i];
            proc(xa.x, ta.x); proc(xa.y, ta.y); proc(xa.z, ta.z); proc(xa.w, ta.w);
        }
    }
    // scalar tail (not hit for the bench shape)
    for (int j = nvec * 4 + gid; j < total; j += stride)
        proc(xs[j], ts[j]);

    __syncthreads();

    // Block reduce. Field safety: <=8192 elems/block -> count < 2^24 at bit
    // 40; sum <= 8192 * 7.4e6 ~ 6e10 < 2^40. No overflow.
    unsigned long long v[BINS];
#pragma unroll
    for (int b = 0; b < BINS; ++b) v[b] = hist[b * BLOCK + tid];
    __syncthreads();                                    // reads done -> reuse

    const int lane = tid & 63;
    const int wid  = tid >> 6;
#pragma unroll
    for (int b = 0; b < BINS; ++b) {
        unsigned long long s = v[b];
#pragma unroll
        for (int off = 32; off > 0; off >>= 1)
            s += __shfl_down(s, off);
        if (lane == 0) hist[wid * BINS + b] = s;
    }
    __syncthreads();
    if (tid < BINS) {
        unsigned long long tot = 0ull;
#pragma unroll
        for (int w = 0; w < BLOCK / 64; ++w) tot += hist[w * BINS + tid];
        unsigned long long sum_fp = tot & ((1ull << 40) - 1ull);
        unsigned int       cntv   = (unsigned int)(tot >> 40);
        psum[(size_t)blockIdx.x * BINS + tid] =
            (float)((double)sum_fp * 9.5367431640625e-7);   // * 2^-20
        pcnt[(size_t)blockIdx.x * BINS + tid] = cntv;
    }
}

// ---------------------------------------------------------------------------
// Pass 2: strided sweep over partials, wave+LDS reduce, fp32 beta math
// exactly as the reference, final scalar.
// ---------------------------------------------------------------------------

__global__ __launch_bounds__(BLOCK) void ghm_pass2(
        const float* __restrict__ psum, const unsigned int* __restrict__ pcnt,
        float* __restrict__ out, int nblocks, float Nf, double inv_total) {
    double       s[BINS];
    unsigned int c[BINS];
#pragma unroll
    for (int b = 0; b < BINS; ++b) { s[b] = 0.0; c[b] = 0u; }

    for (int i = threadIdx.x; i < nblocks; i += BLOCK) {
#pragma unroll
        for (int b = 0; b < BINS; ++b) {
            s[b] += (double)psum[(size_t)i * BINS + b];
            c[b] += pcnt[(size_t)i * BINS + b];
        }
    }

    __shared__ double       ls[BLOCK / 64][BINS];
    __shared__ unsigned int lc[BLOCK / 64][BINS];
    const int lane = threadIdx.x & 63;
    const int wid  = threadIdx.x >> 6;
#pragma unroll
    for (int b = 0; b < BINS; ++b) {
        double       sb = s[b];
        unsigned int cb = c[b];
#pragma unroll
        for (int off = 32; off > 0; off >>= 1) {
            sb += __shfl_down(sb, off);
            cb += __shfl_down(cb, off);
        }
        if (lane == 0) { ls[wid][b] = sb; lc[wid][b] = cb; }
    }
    __syncthreads();

    if (threadIdx.x == 0) {
        double             bin_sum[BINS];
        unsigned long long bin_cnt[BINS];
#pragma unroll
        for (int b = 0; b < BINS; ++b) {
            double ts = 0.0;
            unsigned long long tc = 0;
#pragma unroll
            for (int w = 0; w < BLOCK / 64; ++w) { ts += ls[w][b]; tc += lc[w][b]; }
            bin_sum[b] = ts;
            bin_cnt[b] = tc;
        }
        float nonempty = 0.0f;
#pragma unroll
        for (int b = 0; b < BINS; ++b) nonempty += (bin_cnt[b] > 0) ? 1.0f : 0.0f;
        double acc = 0.0;
#pragma unroll
        for (int b = 0; b < BINS; ++b) {
            float bc   = (float)bin_cnt[b];            // reference keeps fp32
            float gd   = fmaxf(bc * nonempty, 1e-6f);
            float beta = Nf / gd;
            acc += (double)beta * bin_sum[b];
        }
        out[0] = (float)(acc * inv_total);
    }
}

// ---------------------------------------------------------------------------

extern "C" void kernel_launch(void* const* d_in, const int* in_sizes, int n_in,
                              void* d_out, int out_size, void* d_ws, size_t ws_size,
                              hipStream_t stream) {
    const float* x = (const float*)d_in[0];
    const float* t = (const float*)d_in[1];
    const int total = in_sizes[0];          // 1048576 * 16
    const int nvec  = total / 4;
    const int N     = total / 16;           // x.shape[0] (first dim)

    int nblocks = NBLK;
    size_t per_block = (size_t)BINS * (sizeof(float) + sizeof(unsigned int));
    if ((size_t)nblocks * per_block > ws_size) {
        nblocks = (int)(ws_size / per_block);
        if (nblocks < 1) nblocks = 1;
    }

    float*        psum = (float*)d_ws;
    unsigned int* pcnt = (unsigned int*)((char*)d_ws +
                          (size_t)nblocks * BINS * sizeof(float));

    ghm_pass1<<<nblocks, BLOCK, 0, stream>>>(
        (const float4*)x, (const float4*)t, x, t, psum, pcnt, nvec, total);
    ghm_pass2<<<1, BLOCK, 0, stream>>>(
        psum, pcnt, (float*)d_out, nblocks, (float)N, 1.0 / (double)total);
}